// Round 4
// baseline (259.677 us; speedup 1.0000x reference)
//
#include <hip/hip_runtime.h>
#include <math.h>

#define B_ 4
#define H_ 192
#define W_ 192
#define Q_ 160
#define E_ 96
#define M_ 96
#define HW_ (H_ * W_)          // 36864
#define NPIX_ (B_ * HW_)       // 147456
#define TPIX 16                // pixels per tile
#define NTILE_B 2304           // tiles per batch (36864/16)
#define TILES_PER_BLK 9        // 2304 / 256 blocks-per-batch
#define NDICE 1024             // 256 blocks per batch * 4 batches
#define NSMALL 962             // 2 + 384 + 576
#define NBUCKET 64
// ws layout (floats): [0]=class [1]=bce [2]=nll [3]=occ
//   [4   + k*4 + b] k<64 : dice numerator partials
//   [260 + k*4 + b] k<64 : sum_true partials
#define WS_NUM0 4
#define WS_TS0  260
#define WS_TOTAL 516

// ---- DPP wave-64 sum: result lands in lane 63 (rocPRIM sequence) ----
template <int CTRL, int RMASK>
__device__ inline float dpp_add_step(float x) {
    int v = __builtin_amdgcn_update_dpp(0, __float_as_int(x), CTRL, RMASK, 0xF, false);
    return x + __int_as_float(v);
}
__device__ inline float wave_sum63(float x) {
    x = dpp_add_step<0x111, 0xF>(x);  // row_shr:1
    x = dpp_add_step<0x112, 0xF>(x);  // row_shr:2
    x = dpp_add_step<0x114, 0xF>(x);  // row_shr:4
    x = dpp_add_step<0x118, 0xF>(x);  // row_shr:8
    x = dpp_add_step<0x142, 0xA>(x);  // row_bcast:15 -> rows 1,3
    x = dpp_add_step<0x143, 0xC>(x);  // row_bcast:31 -> rows 2,3
    return x;                          // lane 63 = full sum
}

__device__ inline float waveSumAll(float v) {
    for (int m = 32; m > 0; m >>= 1) v += __shfl_xor(v, m, 64);
    return v;
}

__device__ inline float softplusf(float x) {
    return fmaxf(x, 0.f) + log1pf(__expf(-fabsf(x)));
}

// tile byte sizes
#define POR_BYTES (TPIX * Q_ * 4)          // 10240
#define TRU_BYTES (TPIX * E_ * 4)          // 6144
#define TILE_BYTES (POR_BYTES + TRU_BYTES) // 16384
#define POR_F (TPIX * Q_)                  // 2560 floats

// ---------------------------------------------------------------------------
// Fused kernel. Block regions:
//   [0, 1024)        dice (numerator + sum_true), LDS-staged coalesced tiles
//   [1024, 1986)     small: +0 class, +1 nll, +2..385 bce 7x7, +386..961 occ CE
// ---------------------------------------------------------------------------
__global__ __launch_bounds__(256) void fused_kernel(
    const float* __restrict__ logit,    // [640]
    const float* __restrict__ trueseg,  // [B,H,W,E]
    const float* __restrict__ binlog,   // [B,H,W,Q]
    const float* __restrict__ por,      // [B,H,W,Q]
    const float* __restrict__ inc,      // [B,E,2]
    const float* __restrict__ pos,      // [B,Q,2]
    const float* __restrict__ chol,     // [B,Q,2,2]
    const float* __restrict__ occlog,   // [B,H,W,4]
    const int* __restrict__ occtrue,    // [B,H,W]
    const int* __restrict__ mqall,      // [B,M]
    const int* __restrict__ meall,      // [B,M]
    float* __restrict__ ws)
{
    __shared__ float4 tilebuf[TILE_BYTES / 16];   // 16 KB: [0,2560) floats = por, [2560,4096) = true
    __shared__ float red[256];
    __shared__ float sA[4], sT[4];
    __shared__ float lab[B_ * Q_];
    const int tid  = threadIdx.x;
    const int lane = tid & 63;
    const int wid  = tid >> 6;
    const int blk  = blockIdx.x;

    if (blk < NDICE) {
        // ================= dice: numerator + true-sum =================
        const int b = blk >> 8;            // 256 blocks per batch
        const int slot = blk & 255;
        const bool hi = lane < 32;
        const int* mq = mqall + b * M_;
        const int* me = meall + b * M_;
        const int mqa = mq[lane];
        const int mea = me[lane];
        int mqb = 0, meb = 0;
        if (hi) { mqb = mq[64 + lane]; meb = me[64 + lane]; }
        const char* porb = (const char*)(por + (size_t)b * HW_ * Q_);
        const char* trb  = (const char*)(trueseg + (size_t)b * HW_ * E_);

        float4 pf[4];
        // issue coalesced loads of tile t (16 KB contiguous-by-region)
        auto load_tile = [&](int t) {
            const int p0 = (slot + t * 256) * TPIX;            // local pixel start
            const char* gp = porb + (size_t)p0 * (Q_ * 4);
            const char* gt = trb  + (size_t)p0 * (E_ * 4);
            #pragma unroll
            for (int i = 0; i < 4; ++i) {
                int off = tid * 16 + i * 4096;
                pf[i] = (off < POR_BYTES)
                        ? *(const float4*)(gp + off)
                        : *(const float4*)(gt + (off - POR_BYTES));
            }
        };
        auto store_tile = [&]() {
            #pragma unroll
            for (int i = 0; i < 4; ++i) tilebuf[tid + i * 256] = pf[i];
        };

        const float* pl = (const float*)tilebuf;          // [16][160]
        const float* tl = (const float*)tilebuf + POR_F;  // [16][96]
        float an = 0.f;   // numerator (valid on lane 63)
        float at = 0.f;   // true-sum partial (per-lane)

        load_tile(0);
        for (int t = 0; t < TILES_PER_BLK; ++t) {
            store_tile();
            __syncthreads();
            if (t + 1 < TILES_PER_BLK) load_tile(t + 1);   // overlaps compute
            #pragma unroll
            for (int k = 0; k < 4; ++k) {
                const int pix = wid * 4 + k;
                float p0v = pl[pix * Q_ + mqa];
                float t0  = tl[pix * E_ + mea];
                float e1 = 0.f, se1 = 0.f, t1 = 0.f;
                if (hi) {
                    float p1 = pl[pix * Q_ + mqb];
                    t1 = tl[pix * E_ + meb];
                    e1 = __expf(p1);
                    se1 = t1 * e1;
                }
                float e0 = __expf(p0v);
                float s  = wave_sum63(e0 + e1);
                float se = wave_sum63(t0 * e0 + se1);
                an += __fdividef(se, s);
                at += t0 + t1;     // me is a full permutation of 0..95 -> row sum
            }
            __syncthreads();
        }
        float atr = wave_sum63(at);
        if (lane == 63) { sA[wid] = an; sT[wid] = atr; }
        __syncthreads();
        if (tid == 0) {
            float num = sA[0] + sA[1] + sA[2] + sA[3];
            float ts  = sT[0] + sT[1] + sT[2] + sT[3];
            int bucket = blk & (NBUCKET - 1);
            atomicAdd(&ws[WS_NUM0 + bucket * 4 + b], 2.f * num);
            atomicAdd(&ws[WS_TS0  + bucket * 4 + b], ts);
        }
    } else {
        const int s = blk - NDICE;
        float acc = 0.f;
        if (s == 0) {
            // ---- class loss ----
            for (int i = tid; i < B_ * Q_; i += 256) lab[i] = 0.f;
            __syncthreads();
            for (int i = tid; i < B_ * M_; i += 256) {
                int b = i / M_;
                lab[b * Q_ + mqall[i]] = 1.f;
            }
            __syncthreads();
            for (int i = tid; i < B_ * Q_; i += 256) {
                float x = logit[i];
                float z = lab[i];
                float w = z > 0.f ? 1.f : 0.1f;
                acc += w * (softplusf(x) - x * z);
            }
            red[tid] = acc; __syncthreads();
            for (int st = 128; st > 0; st >>= 1) { if (tid < st) red[tid] += red[tid + st]; __syncthreads(); }
            if (tid == 0) ws[0] = red[0];
        } else if (s == 1) {
            // ---- distance NLL ----
            for (int i = tid; i < B_ * M_; i += 256) {
                int b = i / M_;
                int qi = mqall[i];
                int ei = meall[i];
                float px = inc[(b * E_ + ei) * 2 + 0];
                float py = inc[(b * E_ + ei) * 2 + 1];
                float cx = pos[(b * Q_ + qi) * 2 + 0];
                float cy = pos[(b * Q_ + qi) * 2 + 1];
                const float* ch = chol + (size_t)(b * Q_ + qi) * 4;
                float l00 = ch[0], l10 = ch[2], l11 = ch[3];
                float d0 = px - cx, d1 = py - cy;
                float z0 = d0 / l00;
                float z1 = (d1 - l10 * z0) / l11;
                float nll = 0.5f * (z0 * z0 + z1 * z1) + 1.837877066409345f
                            + logf(l00) + logf(l11);
                if (isinf(nll)) nll = 1e7f;
                acc += nll;
            }
            red[tid] = acc; __syncthreads();
            for (int st = 128; st > 0; st >>= 1) { if (tid < st) red[tid] += red[tid + st]; __syncthreads(); }
            if (tid == 0) ws[2] = red[0];
        } else if (s < 386) {
            // ---- 7x7 window BCE, one block per (b, m) ----
            int idx = s - 2;
            int b = idx / M_;
            int ei = meall[idx];
            int qi = mqall[idx];
            float px = inc[(b * E_ + ei) * 2 + 0];
            float py = inc[(b * E_ + ei) * 2 + 1];
            int r0 = (int)floorf(px) - 3;
            int c0 = (int)floorf(py) - 3;
            if (tid < 49) {
                int rr = r0 + tid / 7;
                int cc = c0 + tid % 7;
                size_t pix = ((size_t)b * H_ + rr) * W_ + cc;
                float tv = trueseg[pix * E_ + ei];
                float lg = binlog[pix * Q_ + qi];
                acc = softplusf(lg) - lg * tv;
            }
            red[tid] = acc; __syncthreads();
            for (int st = 128; st > 0; st >>= 1) { if (tid < st) red[tid] += red[tid + st]; __syncthreads(); }
            if (tid == 0) atomicAdd(&ws[1], red[0]);
        } else {
            // ---- occupancy cross-entropy, 256 pixels per block ----
            int p = (s - 386) * 256 + tid;
            if (p < NPIX_) {
                float4 v = *(const float4*)(occlog + (size_t)p * 4);
                int lb = occtrue[p];
                float m = fmaxf(fmaxf(v.x, v.y), fmaxf(v.z, v.w));
                float lse = m + __logf(__expf(v.x - m) + __expf(v.y - m) +
                                       __expf(v.z - m) + __expf(v.w - m));
                float xs = lb == 0 ? v.x : (lb == 1 ? v.y : (lb == 2 ? v.z : v.w));
                acc = lse - xs;
            }
            red[tid] = acc; __syncthreads();
            for (int st = 128; st > 0; st >>= 1) { if (tid < st) red[tid] += red[tid + st]; __syncthreads(); }
            if (tid == 0) atomicAdd(&ws[3], red[0]);
        }
    }
}

// ---------------------------------------------------------------------------
// Final combine: one wave. Lane k owns bucket k.
// ---------------------------------------------------------------------------
__global__ __launch_bounds__(64) void final_kernel(const float* __restrict__ ws,
                                                   float* __restrict__ out)
{
    const int lane = threadIdx.x;
    float n[B_], t[B_];
    for (int b = 0; b < B_; ++b) {
        n[b] = waveSumAll(ws[WS_NUM0 + lane * 4 + b]);
        t[b] = waveSumAll(ws[WS_TS0  + lane * 4 + b]);
    }
    if (lane == 0) {
        float class_l = ws[0] * (1.f / (B_ * Q_));
        float bce_l   = ws[1] * (1.f / (B_ * M_ * 49));
        float nll_l   = ws[2] * (1.f / (B_ * M_));
        float occ_l   = ws[3] * (1.f / NPIX_);
        float dice = 0.f;
        for (int b = 0; b < B_; ++b)
            dice += 1.f - (n[b] + 1.f) / (t[b] + (float)HW_ + 1.f);
        dice *= (1.f / B_);
        out[0] = class_l + bce_l + nll_l + occ_l + dice;
    }
}

extern "C" void kernel_launch(void* const* d_in, const int* in_sizes, int n_in,
                              void* d_out, int out_size, void* d_ws, size_t ws_size,
                              hipStream_t stream) {
    const float* logit   = (const float*)d_in[0];
    const float* trueseg = (const float*)d_in[1];
    const float* binlog  = (const float*)d_in[2];
    const float* por     = (const float*)d_in[3];
    const float* inc     = (const float*)d_in[4];
    const float* pos     = (const float*)d_in[5];
    const float* chol    = (const float*)d_in[6];
    const float* occlog  = (const float*)d_in[7];
    const int*   occtrue = (const int*)d_in[8];
    const int*   mq      = (const int*)d_in[9];
    const int*   me      = (const int*)d_in[10];
    float* out = (float*)d_out;
    float* ws  = (float*)d_ws;

    (void)hipMemsetAsync(d_ws, 0, WS_TOTAL * sizeof(float), stream);

    hipLaunchKernelGGL(fused_kernel, dim3(NDICE + NSMALL), dim3(256), 0, stream,
                       logit, trueseg, binlog, por, inc, pos, chol, occlog, occtrue,
                       mq, me, ws);
    hipLaunchKernelGGL(final_kernel, dim3(1), dim3(64), 0, stream, ws, out);
}

// Round 5
// 242.977 us; speedup vs baseline: 1.0687x; 1.0687x over previous
//
#include <hip/hip_runtime.h>
#include <math.h>

#define B_ 4
#define H_ 192
#define W_ 192
#define Q_ 160
#define E_ 96
#define M_ 96
#define HW_ (H_ * W_)          // 36864
#define NPIX_ (B_ * HW_)       // 147456
#define TPIX 16                // pixels per tile
#define TILES_PER_BLK 9        // 36864 / (256 blocks * 16 px)
#define NDICE 1024             // 256 blocks per batch * 4 batches
#define NSMALL 962             // 2 + 384 + 576
#define NBUCKET 64
// ws layout (floats): [0]=class [1]=bce [2]=nll [3]=occ
//   [4   + k*4 + b] k<64 : dice numerator partials
//   [260 + k*4 + b] k<64 : sum_true partials
#define WS_NUM0 4
#define WS_TS0  260
#define WS_TOTAL 516

#define POR_BYTES (TPIX * Q_ * 4)          // 10240
#define TRU_BYTES (TPIX * E_ * 4)          // 6144
#define TILE_BYTES (POR_BYTES + TRU_BYTES) // 16384
#define POR_F (TPIX * Q_)                  // 2560 floats

// ---- async global->LDS, 16 B per lane; lds dest = wave-uniform base + lane*16 ----
__device__ __forceinline__ void stage16(const void* g, void* l) {
    __builtin_amdgcn_global_load_lds(
        (const __attribute__((address_space(1))) void*)g,
        (__attribute__((address_space(3))) void*)l, 16, 0, 0);
}

// ---- DPP wave-64 sum: result lands in lane 63 ----
template <int CTRL, int RMASK>
__device__ __forceinline__ float dpp_add_step(float x) {
    int v = __builtin_amdgcn_update_dpp(0, __float_as_int(x), CTRL, RMASK, 0xF, false);
    return x + __int_as_float(v);
}
__device__ __forceinline__ float wave_sum63(float x) {
    x = dpp_add_step<0x111, 0xF>(x);  // row_shr:1
    x = dpp_add_step<0x112, 0xF>(x);  // row_shr:2
    x = dpp_add_step<0x114, 0xF>(x);  // row_shr:4
    x = dpp_add_step<0x118, 0xF>(x);  // row_shr:8
    x = dpp_add_step<0x142, 0xA>(x);  // row_bcast:15 -> rows 1,3
    x = dpp_add_step<0x143, 0xC>(x);  // row_bcast:31 -> rows 2,3
    return x;                          // lane 63 = full sum
}

__device__ __forceinline__ float waveSumAll(float v) {
    for (int m = 32; m > 0; m >>= 1) v += __shfl_xor(v, m, 64);
    return v;
}

__device__ __forceinline__ float softplusf(float x) {
    return fmaxf(x, 0.f) + log1pf(__expf(-fabsf(x)));
}

// ---------------------------------------------------------------------------
// Fused kernel. Block regions:
//   [0, 1024)        dice (numerator + sum_true), async-LDS double-buffered tiles
//   [1024, 1986)     small: +0 class, +1 nll, +2..385 bce 7x7, +386..961 occ CE
// ---------------------------------------------------------------------------
__global__ __launch_bounds__(256) void fused_kernel(
    const float* __restrict__ logit,    // [640]
    const float* __restrict__ trueseg,  // [B,H,W,E]
    const float* __restrict__ binlog,   // [B,H,W,Q]
    const float* __restrict__ por,      // [B,H,W,Q]
    const float* __restrict__ inc,      // [B,E,2]
    const float* __restrict__ pos,      // [B,Q,2]
    const float* __restrict__ chol,     // [B,Q,2,2]
    const float* __restrict__ occlog,   // [B,H,W,4]
    const int* __restrict__ occtrue,    // [B,H,W]
    const int* __restrict__ mqall,      // [B,M]
    const int* __restrict__ meall,      // [B,M]
    float* __restrict__ ws)
{
    __shared__ float tilebuf[2 * TILE_BYTES / 4];   // 32 KB: two tile buffers
    __shared__ float sA[4], sT[4];
    const int tid  = threadIdx.x;
    const int lane = tid & 63;
    const int wid  = tid >> 6;
    const int blk  = blockIdx.x;

    if (blk < NDICE) {
        // ================= dice: numerator + true-sum =================
        const int b = blk >> 8;            // 256 blocks per batch
        const int slot = blk & 255;
        const bool hi = lane < 32;
        const int* mq = mqall + b * M_;
        const int* me = meall + b * M_;
        const int mqa = mq[lane];
        const int mea = me[lane];
        int mqb = 0, meb = 0;
        if (hi) { mqb = mq[64 + lane]; meb = me[64 + lane]; }
        const char* porb = (const char*)(por + (size_t)b * HW_ * Q_);
        const char* trb  = (const char*)(trueseg + (size_t)b * HW_ * E_);

        float an = 0.f;   // numerator (valid on lane 63)
        float at = 0.f;   // true-sum partial (per-lane)

        // ---- prologue: stage tile 0 into buffer 0 ----
        {
            const int p0 = slot * TPIX;
            const char* gp = porb + (size_t)p0 * (Q_ * 4);
            const char* gt = trb  + (size_t)p0 * (E_ * 4);
            #pragma unroll
            for (int i = 0; i < 4; ++i) {
                const int off = i * 4096 + wid * 1024;      // wave-uniform
                const char* src = (off < POR_BYTES) ? (gp + off)
                                                    : (gt + (off - POR_BYTES));
                stage16(src + lane * 16, (char*)tilebuf + off);
            }
        }

        int bufsel = 0;
        for (int t = 0; t < TILES_PER_BLK; ++t) {
            __syncthreads();   // drains vmcnt -> buf[bufsel] ready; all waves past prev compute
            if (t + 1 < TILES_PER_BLK) {
                const int p0 = (slot + (t + 1) * 256) * TPIX;
                const char* gp = porb + (size_t)p0 * (Q_ * 4);
                const char* gt = trb  + (size_t)p0 * (E_ * 4);
                const int nb = bufsel ^ 1;
                #pragma unroll
                for (int i = 0; i < 4; ++i) {
                    const int off = i * 4096 + wid * 1024;
                    const char* src = (off < POR_BYTES) ? (gp + off)
                                                        : (gt + (off - POR_BYTES));
                    stage16(src + lane * 16, (char*)tilebuf + nb * TILE_BYTES + off);
                }
            }
            const float* pl = tilebuf + bufsel * (TILE_BYTES / 4);   // [16][160]
            const float* tl = pl + POR_F;                            // [16][96]
            #pragma unroll
            for (int k = 0; k < 4; ++k) {
                const int pix = wid * 4 + k;
                float p0v = pl[pix * Q_ + mqa];
                float t0  = tl[pix * E_ + mea];
                float e1 = 0.f, se1 = 0.f, t1 = 0.f;
                if (hi) {
                    float p1 = pl[pix * Q_ + mqb];
                    t1 = tl[pix * E_ + meb];
                    e1 = __expf(p1);
                    se1 = t1 * e1;
                }
                float e0 = __expf(p0v);
                float s  = wave_sum63(e0 + e1);
                float se = wave_sum63(t0 * e0 + se1);
                an += __fdividef(se, s);
                at += t0 + t1;     // me is a full permutation of 0..95 -> row sum
            }
            bufsel ^= 1;
        }
        float atr = wave_sum63(at);
        if (lane == 63) { sA[wid] = an; sT[wid] = atr; }
        __syncthreads();
        if (tid == 0) {
            float num = sA[0] + sA[1] + sA[2] + sA[3];
            float ts  = sT[0] + sT[1] + sT[2] + sT[3];
            int bucket = blk & (NBUCKET - 1);
            atomicAdd(&ws[WS_NUM0 + bucket * 4 + b], 2.f * num);
            atomicAdd(&ws[WS_TS0  + bucket * 4 + b], ts);
        }
    } else {
        float* red = tilebuf;            // alias: 256 floats
        float* lab = tilebuf + 256;      // alias: 640 floats
        const int s = blk - NDICE;
        float acc = 0.f;
        if (s == 0) {
            // ---- class loss ----
            for (int i = tid; i < B_ * Q_; i += 256) lab[i] = 0.f;
            __syncthreads();
            for (int i = tid; i < B_ * M_; i += 256) {
                int b = i / M_;
                lab[b * Q_ + mqall[i]] = 1.f;
            }
            __syncthreads();
            for (int i = tid; i < B_ * Q_; i += 256) {
                float x = logit[i];
                float z = lab[i];
                float w = z > 0.f ? 1.f : 0.1f;
                acc += w * (softplusf(x) - x * z);
            }
            red[tid] = acc; __syncthreads();
            for (int st = 128; st > 0; st >>= 1) { if (tid < st) red[tid] += red[tid + st]; __syncthreads(); }
            if (tid == 0) ws[0] = red[0];
        } else if (s == 1) {
            // ---- distance NLL ----
            for (int i = tid; i < B_ * M_; i += 256) {
                int b = i / M_;
                int qi = mqall[i];
                int ei = meall[i];
                float px = inc[(b * E_ + ei) * 2 + 0];
                float py = inc[(b * E_ + ei) * 2 + 1];
                float cx = pos[(b * Q_ + qi) * 2 + 0];
                float cy = pos[(b * Q_ + qi) * 2 + 1];
                const float* ch = chol + (size_t)(b * Q_ + qi) * 4;
                float l00 = ch[0], l10 = ch[2], l11 = ch[3];
                float d0 = px - cx, d1 = py - cy;
                float z0 = d0 / l00;
                float z1 = (d1 - l10 * z0) / l11;
                float nll = 0.5f * (z0 * z0 + z1 * z1) + 1.837877066409345f
                            + logf(l00) + logf(l11);
                if (isinf(nll)) nll = 1e7f;
                acc += nll;
            }
            red[tid] = acc; __syncthreads();
            for (int st = 128; st > 0; st >>= 1) { if (tid < st) red[tid] += red[tid + st]; __syncthreads(); }
            if (tid == 0) ws[2] = red[0];
        } else if (s < 386) {
            // ---- 7x7 window BCE, one block per (b, m) ----
            int idx = s - 2;
            int b = idx / M_;
            int ei = meall[idx];
            int qi = mqall[idx];
            float px = inc[(b * E_ + ei) * 2 + 0];
            float py = inc[(b * E_ + ei) * 2 + 1];
            int r0 = (int)floorf(px) - 3;
            int c0 = (int)floorf(py) - 3;
            if (tid < 49) {
                int rr = r0 + tid / 7;
                int cc = c0 + tid % 7;
                size_t pix = ((size_t)b * H_ + rr) * W_ + cc;
                float tv = trueseg[pix * E_ + ei];
                float lg = binlog[pix * Q_ + qi];
                acc = softplusf(lg) - lg * tv;
            }
            red[tid] = acc; __syncthreads();
            for (int st = 128; st > 0; st >>= 1) { if (tid < st) red[tid] += red[tid + st]; __syncthreads(); }
            if (tid == 0) atomicAdd(&ws[1], red[0]);
        } else {
            // ---- occupancy cross-entropy, 256 pixels per block ----
            int p = (s - 386) * 256 + tid;
            if (p < NPIX_) {
                float4 v = *(const float4*)(occlog + (size_t)p * 4);
                int lb = occtrue[p];
                float m = fmaxf(fmaxf(v.x, v.y), fmaxf(v.z, v.w));
                float lse = m + __logf(__expf(v.x - m) + __expf(v.y - m) +
                                       __expf(v.z - m) + __expf(v.w - m));
                float xs = lb == 0 ? v.x : (lb == 1 ? v.y : (lb == 2 ? v.z : v.w));
                acc = lse - xs;
            }
            red[tid] = acc; __syncthreads();
            for (int st = 128; st > 0; st >>= 1) { if (tid < st) red[tid] += red[tid + st]; __syncthreads(); }
            if (tid == 0) atomicAdd(&ws[3], red[0]);
        }
    }
}

// ---------------------------------------------------------------------------
// Final combine: one wave. Lane k owns bucket k.
// ---------------------------------------------------------------------------
__global__ __launch_bounds__(64) void final_kernel(const float* __restrict__ ws,
                                                   float* __restrict__ out)
{
    const int lane = threadIdx.x;
    float n[B_], t[B_];
    for (int b = 0; b < B_; ++b) {
        n[b] = waveSumAll(ws[WS_NUM0 + lane * 4 + b]);
        t[b] = waveSumAll(ws[WS_TS0  + lane * 4 + b]);
    }
    if (lane == 0) {
        float class_l = ws[0] * (1.f / (B_ * Q_));
        float bce_l   = ws[1] * (1.f / (B_ * M_ * 49));
        float nll_l   = ws[2] * (1.f / (B_ * M_));
        float occ_l   = ws[3] * (1.f / NPIX_);
        float dice = 0.f;
        for (int b = 0; b < B_; ++b)
            dice += 1.f - (n[b] + 1.f) / (t[b] + (float)HW_ + 1.f);
        dice *= (1.f / B_);
        out[0] = class_l + bce_l + nll_l + occ_l + dice;
    }
}

extern "C" void kernel_launch(void* const* d_in, const int* in_sizes, int n_in,
                              void* d_out, int out_size, void* d_ws, size_t ws_size,
                              hipStream_t stream) {
    const float* logit   = (const float*)d_in[0];
    const float* trueseg = (const float*)d_in[1];
    const float* binlog  = (const float*)d_in[2];
    const float* por     = (const float*)d_in[3];
    const float* inc     = (const float*)d_in[4];
    const float* pos     = (const float*)d_in[5];
    const float* chol    = (const float*)d_in[6];
    const float* occlog  = (const float*)d_in[7];
    const int*   occtrue = (const int*)d_in[8];
    const int*   mq      = (const int*)d_in[9];
    const int*   me      = (const int*)d_in[10];
    float* out = (float*)d_out;
    float* ws  = (float*)d_ws;

    (void)hipMemsetAsync(d_ws, 0, WS_TOTAL * sizeof(float), stream);

    hipLaunchKernelGGL(fused_kernel, dim3(NDICE + NSMALL), dim3(256), 0, stream,
                       logit, trueseg, binlog, por, inc, pos, chol, occlog, occtrue,
                       mq, me, ws);
    hipLaunchKernelGGL(final_kernel, dim3(1), dim3(64), 0, stream, ws, out);
}